// Round 10
// baseline (1213.107 us; speedup 1.0000x reference)
//
#include <hip/hip_runtime.h>
#include <hip/hip_bf16.h>

typedef __attribute__((ext_vector_type(8))) __bf16 bf16x8;
typedef __attribute__((ext_vector_type(4))) float f32x4;

#define NB 32768
#define HDIM 512
#define KDIM 1024

struct WPtrs { const float* wi[4]; const float* wh[4]; };
struct BPtrs { const float* bi[4]; const float* bh[4]; };

__device__ __forceinline__ float fsigmoid(float x) {
  return 1.0f / (1.0f + __expf(-x));
}
__device__ __forceinline__ float ftanh(float x) {
  return 2.0f / (1.0f + __expf(-2.0f * x)) - 1.0f;
}
__device__ __forceinline__ bf16x8 pack8(float4 a, float4 b) {
  bf16x8 r;
  r[0] = (__bf16)a.x; r[1] = (__bf16)a.y; r[2] = (__bf16)a.z; r[3] = (__bf16)a.w;
  r[4] = (__bf16)b.x; r[5] = (__bf16)b.y; r[6] = (__bf16)b.z; r[7] = (__bf16)b.w;
  return r;
}
__device__ __forceinline__ void gll16(const void* g, void* l) {
  __builtin_amdgcn_global_load_lds(
      (const __attribute__((address_space(1))) void*)g,
      (__attribute__((address_space(3))) void*)l, 16, 0, 0);
}
#define MFMA16(A, B, C) \
  C = __builtin_amdgcn_mfma_f32_16x16x32_bf16(A, B, C, 0, 0, 0)
#define SBAR() __builtin_amdgcn_s_barrier()
#define SCHED0() __builtin_amdgcn_sched_barrier(0)
#define LGKM(n) asm volatile("s_waitcnt lgkmcnt(" #n ")" ::: "memory")
#define VMCNT0() asm volatile("s_waitcnt vmcnt(0)" ::: "memory")

// ====================== prep (verified r1-r9) ======================
__global__ void pack_bias_kernel(BPtrs p, float* __restrict__ bias) {
  int idx = blockIdx.x * 256 + threadIdx.x;
  int g = idx >> 9, np = idx & 511;
  bias[idx] = p.bi[g][np] + p.bh[g][np];
}

__global__ void conv_a_kernel(const float* __restrict__ x,
                              const float* __restrict__ h,
                              __bf16* __restrict__ Abf) {
  const size_t N8 = (size_t)NB * KDIM / 8;
  for (size_t i = (size_t)blockIdx.x * blockDim.x + threadIdx.x; i < N8;
       i += (size_t)gridDim.x * blockDim.x) {
    size_t e = i * 8;
    int k = (int)(e & (KDIM - 1));
    size_t r = e >> 10;
    const float* s = (k < 512) ? (x + r * 512 + k) : (h + r * 512 + (k - 512));
    float4 v0 = *(const float4*)s;
    float4 v1 = *(const float4*)(s + 4);
    *(bf16x8*)(Abf + e) = pack8(v0, v1);
  }
}

__global__ void pack_w2_kernel(WPtrs p, __bf16* __restrict__ Wt) {
  __shared__ float tile[64][65];
  const int kt = blockIdx.x;
  const int nt = blockIdx.y;
  const int g = blockIdx.z;
  const int k0 = kt * 64, n0 = nt * 64;
  const float* src = (k0 < 512) ? p.wi[g] : p.wh[g];
  const int k0l = (k0 < 512) ? k0 : (k0 - 512);
  const int rr = threadIdx.x >> 6;
  const int cc = threadIdx.x & 63;
#pragma unroll
  for (int pp = 0; pp < 16; ++pp) {
    int kk = pp * 4 + rr;
    tile[kk][cc] = src[(size_t)(k0l + kk) * 512 + (n0 + cc)];
  }
  __syncthreads();
#pragma unroll
  for (int pp = 0; pp < 16; ++pp) {
    int nn = pp * 4 + rr;
    int np = n0 + nn;
    int prow = (np >> 6) * 256 + ((g >> 1) << 7) + (((np >> 4) & 3) << 5) +
               ((g & 1) << 4) + (np & 15);
    Wt[(size_t)prow * KDIM + (k0 + cc)] = (__bf16)tile[cc][nn];
  }
}

#define GEMM_SETUP()                                                          \
  __shared__ alignas(16) char lds[131072];                                    \
  const int tid = threadIdx.x;                                                \
  const int wid = tid >> 6;                                                   \
  const int wm = wid >> 2, wn = wid & 3;                                      \
  const int lane = tid & 63;                                                  \
  const int fc = lane & 15, fg = lane >> 4;                                   \
  const int bn = blockIdx.x & 7;                                              \
  const int bmg = blockIdx.x >> 3;                                            \
  const __bf16* Bsrc = Wt + (size_t)(bn * 256) * KDIM;                        \
  const int r0 = tid >> 3;                                                    \
  const int ssl = ((tid & 7) ^ (r0 & 7)) * 8;                                 \
  const uint32_t ldst0 = (uint32_t)(tid >> 6) * 1024;                         \
  auto stA = [&](int t, int h) {                                              \
    if (t < 64) {                                                             \
      const __bf16* g = Abf +                                                 \
                        ((size_t)((bmg << 2) + ((t >> 4) & 3)) * 256 +        \
                         h * 128 + r0) * KDIM + (t & 15) * 64 + ssl;          \
      uint32_t lb = (uint32_t)(t & 1) * 65536 + (uint32_t)h * 16384 + ldst0;  \
      gll16(g, (void*)&lds[lb]);                                              \
      gll16(g + (size_t)64 * KDIM, (void*)&lds[lb + 8192]);                   \
    }                                                                         \
  };                                                                          \
  auto stB = [&](int t, int h) {                                              \
    if (t < 64) {                                                             \
      const __bf16* g =                                                       \
          Bsrc + ((size_t)h * 128 + r0) * KDIM + (t & 15) * 64 + ssl;         \
      uint32_t lb =                                                           \
          (uint32_t)(t & 1) * 65536 + 32768 + (uint32_t)h * 16384 + ldst0;    \
      gll16(g, (void*)&lds[lb]);                                              \
      gll16(g + (size_t)64 * KDIM, (void*)&lds[lb + 8192]);                   \
    }                                                                         \
  };                                                                          \
  auto ldA = [&](int cb, int h, int mq, int ks) -> bf16x8 {                   \
    int row = wm * 64 + mq * 16 + fc;                                         \
    uint32_t off = (uint32_t)cb * 65536 + (uint32_t)h * 16384 +               \
                   (uint32_t)row * 128 +                                      \
                   (uint32_t)(((ks * 4 + fg) ^ (row & 7)) << 4);              \
    return *(const bf16x8*)&lds[off];                                         \
  };                                                                          \
  auto ldB = [&](int cb, int h, int nq, int ks) -> bf16x8 {                   \
    int row = wn * 32 + nq * 16 + fc;                                         \
    uint32_t off = (uint32_t)cb * 65536 + 32768 + (uint32_t)h * 16384 +       \
                   (uint32_t)row * 128 +                                      \
                   (uint32_t)(((ks * 4 + fg) ^ (row & 7)) << 4);              \
    return *(const bf16x8*)&lds[off];                                         \
  };                                                                          \
  f32x4 acc[8][4];                                                            \
  _Pragma("unroll") for (int m = 0; m < 8; ++m)                               \
      _Pragma("unroll") for (int n = 0; n < 4; ++n)                           \
          acc[m][n] = (f32x4){0.f, 0.f, 0.f, 0.f};                            \
  bf16x8 a[4][2], b0[2][2], b1[2][2];

#define Q_GROUP(AKS, BARR, ACCR, ACCC)                                        \
  __builtin_amdgcn_s_setprio(1);                                              \
  _Pragma("unroll") for (int mq = 0; mq < 4; ++mq)                            \
      _Pragma("unroll") for (int nq = 0; nq < 2; ++nq)                        \
          MFMA16(a[mq][AKS], BARR[nq][AKS], acc[ACCR + mq][ACCC + nq]);       \
  __builtin_amdgcn_s_setprio(0);

// ============ real kernel: r9 + per-SIMD anti-phase quadrant rotation ============
// Waves with wm=0 run quadrants (a0b0),(a0b1),(a1b1),(a1b0); waves with wm=1
// run (a1b1),(a1b0),(a0b0),(a0b1). Each SIMD hosts one wave of each parity
// (wid and wid+4 share a SIMD) -> mid-tile LDS/MFMA phases complement.
// Bitwise-safe: each acc frag is touched in exactly ONE quadrant per tile,
// always ks0 then ks1, so per-acc accumulation order is unchanged.
__global__ __launch_bounds__(512, 1) void lstm_gemm8(
    const __bf16* __restrict__ Abf, const __bf16* __restrict__ Wt,
    const float* __restrict__ cin, const float* __restrict__ bias,
    float* __restrict__ out) {
  GEMM_SETUP();

  const int np = bn * 64 + wn * 16 + fc;
  const float bi = bias[np];
  const float bf_ = bias[512 + np];
  const float bg = bias[1024 + np];
  const float bo = bias[1536 + np];
  const size_t couts = (size_t)NB * HDIM;

  stA(0, 0); stA(0, 1); stB(0, 0); stB(0, 1);
  VMCNT0();
  SBAR();

#pragma unroll 2
  for (int t = 0; t < 64; ++t) {
    const int cb = t & 1;
    if (wm == 0) {
      // -------- even parity (r9 order) --------
      b0[0][0] = ldB(cb, 0, 0, 0); b0[1][0] = ldB(cb, 0, 1, 0);
      b0[0][1] = ldB(cb, 0, 0, 1); b0[1][1] = ldB(cb, 0, 1, 1);
      a[0][0] = ldA(cb, 0, 0, 0); a[1][0] = ldA(cb, 0, 1, 0);
      a[2][0] = ldA(cb, 0, 2, 0); a[3][0] = ldA(cb, 0, 3, 0);
      a[0][1] = ldA(cb, 0, 0, 1); a[1][1] = ldA(cb, 0, 1, 1);
      a[2][1] = ldA(cb, 0, 2, 1); a[3][1] = ldA(cb, 0, 3, 1);
      b1[0][0] = ldB(cb, 1, 0, 0); b1[1][0] = ldB(cb, 1, 1, 0);
      b1[0][1] = ldB(cb, 1, 0, 1); b1[1][1] = ldB(cb, 1, 1, 1);
      stA(t + 1, 0); stA(t + 1, 1);
      LGKM(8); SCHED0();
      Q_GROUP(0, b0, 0, 0);
      LGKM(4); SCHED0();
      Q_GROUP(1, b0, 0, 0);
      stB(t + 1, 0);
      LGKM(2); SCHED0();
      Q_GROUP(0, b1, 0, 2);
      LGKM(0); SCHED0();
      Q_GROUP(1, b1, 0, 2);
      stB(t + 1, 1);
      a[0][0] = ldA(cb, 1, 0, 0); a[1][0] = ldA(cb, 1, 1, 0);
      a[2][0] = ldA(cb, 1, 2, 0); a[3][0] = ldA(cb, 1, 3, 0);
      a[0][1] = ldA(cb, 1, 0, 1); a[1][1] = ldA(cb, 1, 1, 1);
      a[2][1] = ldA(cb, 1, 2, 1); a[3][1] = ldA(cb, 1, 3, 1);
      LGKM(4); SCHED0();
      Q_GROUP(0, b1, 4, 2);
      LGKM(0); SCHED0();
      Q_GROUP(1, b1, 4, 2);
      VMCNT0(); SCHED0();
      Q_GROUP(0, b0, 4, 0);
      Q_GROUP(1, b0, 4, 0);
    } else {
      // -------- odd parity (halves swapped; staging order mirrored) --------
      b1[0][0] = ldB(cb, 1, 0, 0); b1[1][0] = ldB(cb, 1, 1, 0);
      b1[0][1] = ldB(cb, 1, 0, 1); b1[1][1] = ldB(cb, 1, 1, 1);
      a[0][0] = ldA(cb, 1, 0, 0); a[1][0] = ldA(cb, 1, 1, 0);
      a[2][0] = ldA(cb, 1, 2, 0); a[3][0] = ldA(cb, 1, 3, 0);
      a[0][1] = ldA(cb, 1, 0, 1); a[1][1] = ldA(cb, 1, 1, 1);
      a[2][1] = ldA(cb, 1, 2, 1); a[3][1] = ldA(cb, 1, 3, 1);
      b0[0][0] = ldB(cb, 0, 0, 0); b0[1][0] = ldB(cb, 0, 1, 0);
      b0[0][1] = ldB(cb, 0, 0, 1); b0[1][1] = ldB(cb, 0, 1, 1);
      stB(t + 1, 0); stB(t + 1, 1);
      LGKM(8); SCHED0();
      Q_GROUP(0, b1, 4, 2);
      LGKM(4); SCHED0();
      Q_GROUP(1, b1, 4, 2);
      stA(t + 1, 0);
      LGKM(2); SCHED0();
      Q_GROUP(0, b0, 4, 0);
      LGKM(0); SCHED0();
      Q_GROUP(1, b0, 4, 0);
      stA(t + 1, 1);
      a[0][0] = ldA(cb, 0, 0, 0); a[1][0] = ldA(cb, 0, 1, 0);
      a[2][0] = ldA(cb, 0, 2, 0); a[3][0] = ldA(cb, 0, 3, 0);
      a[0][1] = ldA(cb, 0, 0, 1); a[1][1] = ldA(cb, 0, 1, 1);
      a[2][1] = ldA(cb, 0, 2, 1); a[3][1] = ldA(cb, 0, 3, 1);
      LGKM(4); SCHED0();
      Q_GROUP(0, b0, 0, 0);
      LGKM(0); SCHED0();
      Q_GROUP(1, b0, 0, 0);
      VMCNT0(); SCHED0();
      Q_GROUP(0, b1, 0, 2);
      Q_GROUP(1, b1, 0, 2);
    }
    SBAR();

    if ((t & 15) == 15) {
      const int g = t >> 4;
#pragma unroll
      for (int mf = 0; mf < 8; ++mf) {
        const int grow0 = ((bmg << 2) + g) * 256 + (mf >> 2) * 128 + wm * 64 +
                          (mf & 3) * 16 + fg * 4;
#pragma unroll
        for (int j = 0; j < 4; ++j) {
          const size_t off = (size_t)(grow0 + j) * HDIM + np;
          float i_ = fsigmoid(acc[mf][0][j] + bi);
          float f_ = fsigmoid(acc[mf][1][j] + bf_);
          float g_ = fsigmoid(acc[mf][2][j] + bg);
          float o_ = fsigmoid(acc[mf][3][j] + bo);
          float cp = f_ * cin[off] + i_ * g_;
          out[off] = o_ * ftanh(cp);
          out[couts + off] = cp;
        }
#pragma unroll
        for (int n = 0; n < 4; ++n) acc[mf][n] = (f32x4){0.f, 0.f, 0.f, 0.f};
      }
    }
  }
}

// ====================== FULL-SIZE diagnostics (192 iters -> top-5 visible) ======================
// diag_lds: ds_read staircase + MFMA + barrier, NO staging/vmcnt in loop.
__global__ __launch_bounds__(512, 1) void diag_lds(
    const __bf16* __restrict__ Abf, const __bf16* __restrict__ Wt,
    float* __restrict__ sink) {
  GEMM_SETUP();
  stA(0, 0); stA(0, 1); stB(0, 0); stB(0, 1);
  stA(1, 0); stA(1, 1); stB(1, 0); stB(1, 1);
  VMCNT0();
  SBAR();
#pragma unroll 2
  for (int t = 0; t < 192; ++t) {
    const int cb = t & 1;
    b0[0][0] = ldB(cb, 0, 0, 0); b0[1][0] = ldB(cb, 0, 1, 0);
    b0[0][1] = ldB(cb, 0, 0, 1); b0[1][1] = ldB(cb, 0, 1, 1);
    a[0][0] = ldA(cb, 0, 0, 0); a[1][0] = ldA(cb, 0, 1, 0);
    a[2][0] = ldA(cb, 0, 2, 0); a[3][0] = ldA(cb, 0, 3, 0);
    a[0][1] = ldA(cb, 0, 0, 1); a[1][1] = ldA(cb, 0, 1, 1);
    a[2][1] = ldA(cb, 0, 2, 1); a[3][1] = ldA(cb, 0, 3, 1);
    b1[0][0] = ldB(cb, 1, 0, 0); b1[1][0] = ldB(cb, 1, 1, 0);
    b1[0][1] = ldB(cb, 1, 0, 1); b1[1][1] = ldB(cb, 1, 1, 1);
    LGKM(8); SCHED0();
    Q_GROUP(0, b0, 0, 0);
    LGKM(4); SCHED0();
    Q_GROUP(1, b0, 0, 0);
    LGKM(2); SCHED0();
    Q_GROUP(0, b1, 0, 2);
    LGKM(0); SCHED0();
    Q_GROUP(1, b1, 0, 2);
    a[0][0] = ldA(cb, 1, 0, 0); a[1][0] = ldA(cb, 1, 1, 0);
    a[2][0] = ldA(cb, 1, 2, 0); a[3][0] = ldA(cb, 1, 3, 0);
    a[0][1] = ldA(cb, 1, 0, 1); a[1][1] = ldA(cb, 1, 1, 1);
    a[2][1] = ldA(cb, 1, 2, 1); a[3][1] = ldA(cb, 1, 3, 1);
    LGKM(4); SCHED0();
    Q_GROUP(0, b1, 4, 2);
    LGKM(0); SCHED0();
    Q_GROUP(1, b1, 4, 2);
    Q_GROUP(0, b0, 4, 0);
    Q_GROUP(1, b0, 4, 0);
    SBAR();
  }
  float s = 0.f;
#pragma unroll
  for (int m = 0; m < 8; ++m)
#pragma unroll
    for (int n = 0; n < 4; ++n)
#pragma unroll
      for (int j = 0; j < 4; ++j) s += acc[m][n][j];
  sink[(blockIdx.x * 512 + tid) & 2047] = s;
}

// diag_stage: staging + VMCNT0 + barrier + MFMA, NO ds_reads in loop.
__global__ __launch_bounds__(512, 1) void diag_stage(
    const __bf16* __restrict__ Abf, const __bf16* __restrict__ Wt,
    float* __restrict__ sink) {
  GEMM_SETUP();
  stA(0, 0); stA(0, 1); stB(0, 0); stB(0, 1);
  VMCNT0();
  SBAR();
#pragma unroll
  for (int mq = 0; mq < 4; ++mq)
#pragma unroll
    for (int ks = 0; ks < 2; ++ks) a[mq][ks] = ldA(0, 0, mq, ks);
#pragma unroll
  for (int nq = 0; nq < 2; ++nq)
#pragma unroll
    for (int ks = 0; ks < 2; ++ks) {
      b0[nq][ks] = ldB(0, 0, nq, ks);
      b1[nq][ks] = ldB(0, 1, nq, ks);
    }
  LGKM(0);
  SBAR();
#pragma unroll 2
  for (int t = 0; t < 192; ++t) {
    stA((t + 1) & 63, 0); stA((t + 1) & 63, 1);
    Q_GROUP(0, b0, 0, 0); Q_GROUP(1, b0, 0, 0);
    stB((t + 1) & 63, 0);
    Q_GROUP(0, b1, 0, 2); Q_GROUP(1, b1, 0, 2);
    stB((t + 1) & 63, 1);
    Q_GROUP(0, b1, 4, 2); Q_GROUP(1, b1, 4, 2);
    VMCNT0(); SCHED0();
    Q_GROUP(0, b0, 4, 0); Q_GROUP(1, b0, 4, 0);
    SBAR();
  }
  float s = 0.f;
#pragma unroll
  for (int m = 0; m < 8; ++m)
#pragma unroll
    for (int n = 0; n < 4; ++n)
#pragma unroll
      for (int j = 0; j < 4; ++j) s += acc[m][n][j];
  sink[(blockIdx.x * 512 + tid) & 2047] = s;
}

// ====================== launch ======================
extern "C" void kernel_launch(void* const* d_in, const int* in_sizes, int n_in,
                              void* d_out, int out_size, void* d_ws,
                              size_t ws_size, hipStream_t stream) {
  const float* xin = (const float*)d_in[0];
  const float* hin = (const float*)d_in[1];
  const float* cin = (const float*)d_in[2];
  WPtrs wp;
  wp.wi[0] = (const float*)d_in[3];
  wp.wi[1] = (const float*)d_in[7];
  wp.wi[2] = (const float*)d_in[11];
  wp.wi[3] = (const float*)d_in[15];
  wp.wh[0] = (const float*)d_in[4];
  wp.wh[1] = (const float*)d_in[8];
  wp.wh[2] = (const float*)d_in[12];
  wp.wh[3] = (const float*)d_in[16];
  BPtrs bp;
  bp.bi[0] = (const float*)d_in[5];
  bp.bi[1] = (const float*)d_in[9];
  bp.bi[2] = (const float*)d_in[13];
  bp.bi[3] = (const float*)d_in[17];
  bp.bh[0] = (const float*)d_in[6];
  bp.bh[1] = (const float*)d_in[10];
  bp.bh[2] = (const float*)d_in[14];
  bp.bh[3] = (const float*)d_in[18];

  const size_t needA = (size_t)NB * KDIM * 2;    // 64 MiB
  const size_t needW = (size_t)2048 * KDIM * 2;  // 4 MiB

  __bf16* Abf = (__bf16*)d_ws;
  __bf16* Wt = (__bf16*)((char*)d_ws + needA);
  float* bias = (float*)((char*)d_ws + needA + needW);

  conv_a_kernel<<<2048, 256, 0, stream>>>(xin, hin, Abf);
  pack_w2_kernel<<<dim3(16, 8, 4), 256, 0, stream>>>(wp, Wt);
  pack_bias_kernel<<<8, 256, 0, stream>>>(bp, bias);
  lstm_gemm8<<<256, 512, 0, stream>>>(Abf, Wt, cin, bias, (float*)d_out);
  // full-size diagnostics AFTER the real kernel (sink = bias area, repacked
  // at the start of every kernel_launch -> deterministic)
  diag_lds<<<256, 512, 0, stream>>>(Abf, Wt, bias);
  diag_stage<<<256, 512, 0, stream>>>(Abf, Wt, bias);
}

// Round 11
// 222.638 us; speedup vs baseline: 5.4488x; 5.4488x over previous
//
#include <hip/hip_runtime.h>
#include <hip/hip_bf16.h>

typedef __attribute__((ext_vector_type(8))) __bf16 bf16x8;
typedef __attribute__((ext_vector_type(4))) float f32x4;
typedef __attribute__((ext_vector_type(16))) float f32x16;

#define NB 32768
#define HDIM 512
#define KDIM 1024

struct WPtrs { const float* wi[4]; const float* wh[4]; };
struct BPtrs { const float* bi[4]; const float* bh[4]; };

__device__ __forceinline__ float fsigmoid(float x) {
  return 1.0f / (1.0f + __expf(-x));
}
__device__ __forceinline__ float ftanh(float x) {
  return 2.0f / (1.0f + __expf(-2.0f * x)) - 1.0f;
}
__device__ __forceinline__ bf16x8 pack8(float4 a, float4 b) {
  bf16x8 r;
  r[0] = (__bf16)a.x; r[1] = (__bf16)a.y; r[2] = (__bf16)a.z; r[3] = (__bf16)a.w;
  r[4] = (__bf16)b.x; r[5] = (__bf16)b.y; r[6] = (__bf16)b.z; r[7] = (__bf16)b.w;
  return r;
}
__device__ __forceinline__ void gll16(const void* g, void* l) {
  __builtin_amdgcn_global_load_lds(
      (const __attribute__((address_space(1))) void*)g,
      (__attribute__((address_space(3))) void*)l, 16, 0, 0);
}
#define MFMA32(A, B, C) \
  C = __builtin_amdgcn_mfma_f32_32x32x16_bf16(A, B, C, 0, 0, 0)
#define SBAR() __builtin_amdgcn_s_barrier()
#define SCHED0() __builtin_amdgcn_sched_barrier(0)
#define LGKM(n) asm volatile("s_waitcnt lgkmcnt(" #n ")" ::: "memory")
#define VMCNT0() asm volatile("s_waitcnt vmcnt(0)" ::: "memory")

// ====================== prep ======================
__global__ void pack_bias_kernel(BPtrs p, float* __restrict__ bias) {
  int idx = blockIdx.x * 256 + threadIdx.x;
  int g = idx >> 9, np = idx & 511;
  bias[idx] = p.bi[g][np] + p.bh[g][np];
}

// A = [x | h] -> bf16 [32768][1024]
__global__ void conv_a_kernel(const float* __restrict__ x,
                              const float* __restrict__ h,
                              __bf16* __restrict__ Abf) {
  const size_t N8 = (size_t)NB * KDIM / 8;
  for (size_t i = (size_t)blockIdx.x * blockDim.x + threadIdx.x; i < N8;
       i += (size_t)gridDim.x * blockDim.x) {
    size_t e = i * 8;
    int k = (int)(e & (KDIM - 1));
    size_t r = e >> 10;
    const float* s = (k < 512) ? (x + r * 512 + k) : (h + r * 512 + (k - 512));
    float4 v0 = *(const float4*)s;
    float4 v1 = *(const float4*)(s + 4);
    *(bf16x8*)(Abf + e) = pack8(v0, v1);
  }
}

// Wt[p][k], p(np,g) = (np>>5)*128 + g*32 + (np&31)  (r1-verified pack)
// -> wave (wn) owns 128 wt-rows = 32 np x 4 gates; gate g = B-frag g, in-lane.
__global__ void pack_w1_kernel(WPtrs p, __bf16* __restrict__ Wt) {
  __shared__ float tile[64][65];
  const int kt = blockIdx.x;  // 16 k-tiles of 64
  const int nt = blockIdx.y;  // 8 np-tiles of 64
  const int g = blockIdx.z;   // gate
  const int k0 = kt * 64, n0 = nt * 64;
  const float* src = (k0 < 512) ? p.wi[g] : p.wh[g];
  const int k0l = (k0 < 512) ? k0 : (k0 - 512);
  const int rr = threadIdx.x >> 6;
  const int cc = threadIdx.x & 63;
#pragma unroll
  for (int pp = 0; pp < 16; ++pp) {
    int kk = pp * 4 + rr;
    tile[kk][cc] = src[(size_t)(k0l + kk) * 512 + (n0 + cc)];
  }
  __syncthreads();
#pragma unroll
  for (int pp = 0; pp < 16; ++pp) {
    int nn = pp * 4 + rr;
    int np = n0 + nn;
    int prow = ((np >> 5) << 7) + g * 32 + (np & 31);
    Wt[(size_t)prow * KDIM + (k0 + cc)] = (__bf16)tile[cc][nn];
  }
}

// ============ main: r5 chassis + 32x32x16 MFMA (half the instructions) ============
// Geometry: block 256 rows x 256 wt-cols (64 np x 4 gates), 8 waves 4M x 2N.
// Wave tile = 64 rows x 128 wt-cols = 2 row-frags x 4 gate-frags of 32x32.
// Frag layouts (generalized from the verified 16x16 kernel + m74/m101 C/D):
//   A/B in: row|col = lane&31, k = (lane>>5)*8 + j  (one ds_read_b128/frag)
//   C/D:    col = lane&31, row = (reg&3) + 8*(reg>>2) + 4*(lane>>5)
// LDS layout, staging, swizzle, prologue, depth-1 vmcnt(0)+SBAR: r5-identical.
__global__ __launch_bounds__(512, 1) void lstm_gemm9(
    const __bf16* __restrict__ Abf, const __bf16* __restrict__ Wt,
    const float* __restrict__ cin, const float* __restrict__ bias,
    float* __restrict__ out) {
  __shared__ alignas(16) char lds[131072];
  const int tid = threadIdx.x;
  const int wid = tid >> 6;
  const int wm = wid >> 1, wn = wid & 1;  // 4M x 2N waves
  const int lane = tid & 63;
  const int l31 = lane & 31, kg = lane >> 5;

  const int bn = blockIdx.x & 7;    // one bn-panel per XCD (B L2-hot)
  const int bmg = blockIdx.x >> 3;  // 0..31, each covers 4 x 256 rows

  const __bf16* Bsrc = Wt + (size_t)(bn * 256) * KDIM;

  const int r0 = tid >> 3;                     // 0..63 staging row
  const int ssl = ((tid & 7) ^ (r0 & 7)) * 8;  // inverse-swizzled k-slot
  const uint32_t ldst0 = (uint32_t)wid * 1024;

  f32x16 acc[2][4];
#pragma unroll
  for (int m = 0; m < 2; ++m)
#pragma unroll
    for (int g = 0; g < 4; ++g)
#pragma unroll
      for (int r = 0; r < 16; ++r) acc[m][g][r] = 0.f;

  bf16x8 aa[2][2], bb[2][4];  // [slot][m] / [slot][gate]

  auto stA = [&](int t, int h) {
    if (t < 64) {
      const __bf16* g = Abf +
                        ((size_t)((bmg << 2) + (t >> 4)) * 256 + h * 128 + r0) *
                            KDIM +
                        (t & 15) * 64 + ssl;
      uint32_t lb = (uint32_t)(t & 1) * 65536 + (uint32_t)h * 16384 + ldst0;
      gll16(g, (void*)&lds[lb]);
      gll16(g + (size_t)64 * KDIM, (void*)&lds[lb + 8192]);
    }
  };
  auto stB = [&](int t, int h) {
    if (t < 64) {
      const __bf16* g =
          Bsrc + ((size_t)h * 128 + r0) * KDIM + (t & 15) * 64 + ssl;
      uint32_t lb =
          (uint32_t)(t & 1) * 65536 + 32768 + (uint32_t)h * 16384 + ldst0;
      gll16(g, (void*)&lds[lb]);
      gll16(g + (size_t)64 * KDIM, (void*)&lds[lb + 8192]);
    }
  };
  // A frag: rows wm*64 + m*32 + l31, k-slice ks (16 k): slot = ks*2 + kg
  auto ldA = [&](int cb, int m, int ks) -> bf16x8 {
    int row = wm * 64 + m * 32 + l31;  // 0..255
    int h = row >> 7, lr = row & 127;
    uint32_t off = (uint32_t)cb * 65536 + (uint32_t)h * 16384 +
                   (uint32_t)lr * 128 +
                   (uint32_t)(((ks * 2 + kg) ^ (lr & 7)) << 4);
    return *(const bf16x8*)&lds[off];
  };
  // B frag (gate g): wt-rows wn*128 + g*32 + l31
  auto ldB = [&](int cb, int g, int ks) -> bf16x8 {
    int lr = g * 32 + l31;  // 0..127 within half wn
    uint32_t off = (uint32_t)cb * 65536 + 32768 + (uint32_t)wn * 16384 +
                   (uint32_t)lr * 128 +
                   (uint32_t)(((ks * 2 + kg) ^ (lr & 7)) << 4);
    return *(const bf16x8*)&lds[off];
  };

  // hoisted epilogue constants
  const int np = bn * 64 + wn * 32 + l31;
  const float bi = bias[np];
  const float bf_ = bias[512 + np];
  const float bg = bias[1024 + np];
  const float bo = bias[1536 + np];
  const size_t couts = (size_t)NB * HDIM;

  // prologue: stage tile 0, drain, barrier (r5-proven)
  stA(0, 0); stA(0, 1); stB(0, 0); stB(0, 1);
  VMCNT0();
  SBAR();

#pragma unroll 2
  for (int t = 0; t < 64; ++t) {
    const int cb = t & 1;
    // issue ks0+ks1 reads (12), in-order: b@ks0 x4, a@ks0 x2, b@ks1 x4, a@ks1 x2
    bb[0][0] = ldB(cb, 0, 0); bb[0][1] = ldB(cb, 1, 0);
    bb[0][2] = ldB(cb, 2, 0); bb[0][3] = ldB(cb, 3, 0);
    aa[0][0] = ldA(cb, 0, 0); aa[0][1] = ldA(cb, 1, 0);
    bb[1][0] = ldB(cb, 0, 1); bb[1][1] = ldB(cb, 1, 1);
    bb[1][2] = ldB(cb, 2, 1); bb[1][3] = ldB(cb, 3, 1);
    aa[1][0] = ldA(cb, 0, 1); aa[1][1] = ldA(cb, 1, 1);
    stA(t + 1, 0); stA(t + 1, 1);
    // ---- ks0 group (needs first 6 reads) ----
    LGKM(6); SCHED0();
    __builtin_amdgcn_s_setprio(1);
#pragma unroll
    for (int m = 0; m < 2; ++m)
#pragma unroll
      for (int g = 0; g < 4; ++g) MFMA32(aa[0][m], bb[0][g], acc[m][g]);
    __builtin_amdgcn_s_setprio(0);
    // issue ks2 into slot 0
    bb[0][0] = ldB(cb, 0, 2); bb[0][1] = ldB(cb, 1, 2);
    bb[0][2] = ldB(cb, 2, 2); bb[0][3] = ldB(cb, 3, 2);
    aa[0][0] = ldA(cb, 0, 2); aa[0][1] = ldA(cb, 1, 2);
    stB(t + 1, 0);
    // ---- ks1 group ----
    LGKM(6); SCHED0();
    __builtin_amdgcn_s_setprio(1);
#pragma unroll
    for (int m = 0; m < 2; ++m)
#pragma unroll
      for (int g = 0; g < 4; ++g) MFMA32(aa[1][m], bb[1][g], acc[m][g]);
    __builtin_amdgcn_s_setprio(0);
    // issue ks3 into slot 1
    bb[1][0] = ldB(cb, 0, 3); bb[1][1] = ldB(cb, 1, 3);
    bb[1][2] = ldB(cb, 2, 3); bb[1][3] = ldB(cb, 3, 3);
    aa[1][0] = ldA(cb, 0, 3); aa[1][1] = ldA(cb, 1, 3);
    stB(t + 1, 1);
    // ---- ks2 group ----
    LGKM(6); SCHED0();
    __builtin_amdgcn_s_setprio(1);
#pragma unroll
    for (int m = 0; m < 2; ++m)
#pragma unroll
      for (int g = 0; g < 4; ++g) MFMA32(aa[0][m], bb[0][g], acc[m][g]);
    __builtin_amdgcn_s_setprio(0);
    // ---- ks3 group; drain stage(t+1) ----
    LGKM(0); VMCNT0(); SCHED0();
    __builtin_amdgcn_s_setprio(1);
#pragma unroll
    for (int m = 0; m < 2; ++m)
#pragma unroll
      for (int g = 0; g < 4; ++g) MFMA32(aa[1][m], bb[1][g], acc[m][g]);
    __builtin_amdgcn_s_setprio(0);
    SBAR();

    // ---- inline LSTM epilogue at group end (regs+global only) ----
    if ((t & 15) == 15) {
      const int grp = t >> 4;
#pragma unroll
      for (int m = 0; m < 2; ++m) {
        const int rowbase =
            ((bmg << 2) + grp) * 256 + wm * 64 + m * 32 + kg * 4;
#pragma unroll
        for (int r = 0; r < 16; ++r) {
          const int row = rowbase + (r & 3) + 8 * (r >> 2);
          const size_t off = (size_t)row * HDIM + np;
          float i_ = fsigmoid(acc[m][0][r] + bi);
          float f_ = fsigmoid(acc[m][1][r] + bf_);
          float g_ = fsigmoid(acc[m][2][r] + bg);
          float o_ = fsigmoid(acc[m][3][r] + bo);
          float cp = f_ * cin[off] + i_ * g_;
          out[off] = o_ * ftanh(cp);
          out[couts + off] = cp;
        }
#pragma unroll
        for (int g = 0; g < 4; ++g)
#pragma unroll
          for (int r = 0; r < 16; ++r) acc[m][g][r] = 0.f;
      }
    }
  }
}

// ====================== launch ======================
extern "C" void kernel_launch(void* const* d_in, const int* in_sizes, int n_in,
                              void* d_out, int out_size, void* d_ws,
                              size_t ws_size, hipStream_t stream) {
  const float* xin = (const float*)d_in[0];
  const float* hin = (const float*)d_in[1];
  const float* cin = (const float*)d_in[2];
  WPtrs wp;
  wp.wi[0] = (const float*)d_in[3];
  wp.wi[1] = (const float*)d_in[7];
  wp.wi[2] = (const float*)d_in[11];
  wp.wi[3] = (const float*)d_in[15];
  wp.wh[0] = (const float*)d_in[4];
  wp.wh[1] = (const float*)d_in[8];
  wp.wh[2] = (const float*)d_in[12];
  wp.wh[3] = (const float*)d_in[16];
  BPtrs bp;
  bp.bi[0] = (const float*)d_in[5];
  bp.bi[1] = (const float*)d_in[9];
  bp.bi[2] = (const float*)d_in[13];
  bp.bi[3] = (const float*)d_in[17];
  bp.bh[0] = (const float*)d_in[6];
  bp.bh[1] = (const float*)d_in[10];
  bp.bh[2] = (const float*)d_in[14];
  bp.bh[3] = (const float*)d_in[18];

  const size_t needA = (size_t)NB * KDIM * 2;    // 64 MiB
  const size_t needW = (size_t)2048 * KDIM * 2;  // 4 MiB

  __bf16* Abf = (__bf16*)d_ws;
  __bf16* Wt = (__bf16*)((char*)d_ws + needA);
  float* bias = (float*)((char*)d_ws + needA + needW);

  conv_a_kernel<<<2048, 256, 0, stream>>>(xin, hin, Abf);
  pack_w1_kernel<<<dim3(16, 8, 4), 256, 0, stream>>>(wp, Wt);
  pack_bias_kernel<<<8, 256, 0, stream>>>(bp, bias);
  lstm_gemm9<<<256, 512, 0, stream>>>(Abf, Wt, cin, bias, (float*)d_out);
}

// Round 13
// 204.419 us; speedup vs baseline: 5.9344x; 1.0891x over previous
//
#include <hip/hip_runtime.h>
#include <hip/hip_bf16.h>

typedef __attribute__((ext_vector_type(8))) __bf16 bf16x8;
typedef __attribute__((ext_vector_type(4))) float f32x4;

#define NB 32768
#define HDIM 512
#define KDIM 1024

struct WPtrs { const float* wi[4]; const float* wh[4]; };
struct BPtrs { const float* bi[4]; const float* bh[4]; };

__device__ __forceinline__ float fsigmoid(float x) {
  return 1.0f / (1.0f + __expf(-x));
}
__device__ __forceinline__ float ftanh(float x) {
  return 2.0f / (1.0f + __expf(-2.0f * x)) - 1.0f;
}
__device__ __forceinline__ bf16x8 pack8(float4 a, float4 b) {
  bf16x8 r;
  r[0] = (__bf16)a.x; r[1] = (__bf16)a.y; r[2] = (__bf16)a.z; r[3] = (__bf16)a.w;
  r[4] = (__bf16)b.x; r[5] = (__bf16)b.y; r[6] = (__bf16)b.z; r[7] = (__bf16)b.w;
  return r;
}
__device__ __forceinline__ void gll16(const void* g, void* l) {
  __builtin_amdgcn_global_load_lds(
      (const __attribute__((address_space(1))) void*)g,
      (__attribute__((address_space(3))) void*)l, 16, 0, 0);
}
#define MFMA16(A, B, C) \
  C = __builtin_amdgcn_mfma_f32_16x16x32_bf16(A, B, C, 0, 0, 0)
#define SBAR() __builtin_amdgcn_s_barrier()
#define SCHED0() __builtin_amdgcn_sched_barrier(0)

// ====================== prep (verified r1-r9) ======================
__global__ void pack_bias_kernel(BPtrs p, float* __restrict__ bias) {
  int idx = blockIdx.x * 256 + threadIdx.x;  // 0..2047
  int g = idx >> 9, np = idx & 511;
  bias[idx] = p.bi[g][np] + p.bh[g][np];
}

// A = [x | h] -> bf16 [32768][1024]
__global__ void conv_a_kernel(const float* __restrict__ x,
                              const float* __restrict__ h,
                              __bf16* __restrict__ Abf) {
  const size_t N8 = (size_t)NB * KDIM / 8;
  for (size_t i = (size_t)blockIdx.x * blockDim.x + threadIdx.x; i < N8;
       i += (size_t)gridDim.x * blockDim.x) {
    size_t e = i * 8;
    int k = (int)(e & (KDIM - 1));
    size_t r = e >> 10;
    const float* s = (k < 512) ? (x + r * 512 + k) : (h + r * 512 + (k - 512));
    float4 v0 = *(const float4*)s;
    float4 v1 = *(const float4*)(s + 4);
    *(bf16x8*)(Abf + e) = pack8(v0, v1);
  }
}

// Wt[p][k], p(np,g) = (np>>6)*256 + (g>>1)*128 + ((np>>4)&3)*32 + (g&1)*16 + (np&15)
__global__ void pack_w2_kernel(WPtrs p, __bf16* __restrict__ Wt) {
  __shared__ float tile[64][65];
  const int kt = blockIdx.x;  // 16 k-tiles of 64
  const int nt = blockIdx.y;  // 8 np-tiles of 64
  const int g = blockIdx.z;   // gate
  const int k0 = kt * 64, n0 = nt * 64;
  const float* src = (k0 < 512) ? p.wi[g] : p.wh[g];
  const int k0l = (k0 < 512) ? k0 : (k0 - 512);
  const int rr = threadIdx.x >> 6;
  const int cc = threadIdx.x & 63;
#pragma unroll
  for (int pp = 0; pp < 16; ++pp) {
    int kk = pp * 4 + rr;
    tile[kk][cc] = src[(size_t)(k0l + kk) * 512 + (n0 + cc)];
  }
  __syncthreads();
#pragma unroll
  for (int pp = 0; pp < 16; ++pp) {
    int nn = pp * 4 + rr;
    int np = n0 + nn;
    int prow = (np >> 6) * 256 + ((g >> 1) << 7) + (((np >> 4) & 3) << 5) +
               ((g & 1) << 4) + (np & 15);
    Wt[(size_t)prow * KDIM + (k0 + cc)] = (__bf16)tile[cc][nn];
  }
}

// ====================== persistent main: ONE barrier per K-tile (r5, best) ======================
// Ledger note: this exact kernel measured 171 µs / MfmaUtil 35% / 0 bank
// conflicts (round 5) — the best of 10 structural variants (8-phase dbl-bar,
// counted-lgkm, ring-4 depth-2, 2-blk/CU, anti-phase, ks-outer, 32x32 all
// ≤ this). Matches the learn_hip K=1024 plateau (m248: 848 TF with the full
// verified technique stack). Kept verbatim.
__global__ __launch_bounds__(512, 1) void lstm_gemm5(
    const __bf16* __restrict__ Abf, const __bf16* __restrict__ Wt,
    const float* __restrict__ cin, const float* __restrict__ bias,
    float* __restrict__ out) {
  __shared__ alignas(16) char lds[131072];
  const int tid = threadIdx.x;
  const int wid = tid >> 6;
  const int wm = wid >> 2, wn = wid & 3;
  const int lane = tid & 63;
  const int fc = lane & 15, fg = lane >> 4;

  const int bn = blockIdx.x & 7;    // one bn-panel per XCD (B stays L2-hot)
  const int bmg = blockIdx.x >> 3;  // 0..31, each covers 4 x 256 rows

  const __bf16* Bsrc = Wt + (size_t)(bn * 256) * KDIM;

  const int r0 = tid >> 3;                     // 0..63
  const int ssl = ((tid & 7) ^ (r0 & 7)) * 8;  // inverse-swizzled k-slot
  const uint32_t ldst0 = (uint32_t)(tid >> 6) * 1024;

  f32x4 acc[8][4];
#pragma unroll
  for (int m = 0; m < 8; ++m)
#pragma unroll
    for (int n = 0; n < 4; ++n) acc[m][n] = (f32x4){0.f, 0.f, 0.f, 0.f};

  bf16x8 a[4][2], b0[2][2], b1[2][2];

  auto stA = [&](int t, int h) {
    if (t < 64) {
      const __bf16* g = Abf +
                        ((size_t)((bmg << 2) + (t >> 4)) * 256 + h * 128 + r0) *
                            KDIM +
                        (t & 15) * 64 + ssl;
      uint32_t lb = (uint32_t)(t & 1) * 65536 + (uint32_t)h * 16384 + ldst0;
      gll16(g, (void*)&lds[lb]);
      gll16(g + (size_t)64 * KDIM, (void*)&lds[lb + 8192]);
    }
  };
  auto stB = [&](int t, int h) {
    if (t < 64) {
      const __bf16* g =
          Bsrc + ((size_t)h * 128 + r0) * KDIM + (t & 15) * 64 + ssl;
      uint32_t lb =
          (uint32_t)(t & 1) * 65536 + 32768 + (uint32_t)h * 16384 + ldst0;
      gll16(g, (void*)&lds[lb]);
      gll16(g + (size_t)64 * KDIM, (void*)&lds[lb + 8192]);
    }
  };
  auto ldA = [&](int cb, int h, int mq, int ks) -> bf16x8 {
    int row = wm * 64 + mq * 16 + fc;
    uint32_t off = (uint32_t)cb * 65536 + (uint32_t)h * 16384 +
                   (uint32_t)row * 128 +
                   (uint32_t)(((ks * 4 + fg) ^ (row & 7)) << 4);
    return *(const bf16x8*)&lds[off];
  };
  auto ldB = [&](int cb, int h, int nq, int ks) -> bf16x8 {
    int row = wn * 32 + nq * 16 + fc;
    uint32_t off = (uint32_t)cb * 65536 + 32768 + (uint32_t)h * 16384 +
                   (uint32_t)row * 128 +
                   (uint32_t)(((ks * 4 + fg) ^ (row & 7)) << 4);
    return *(const bf16x8*)&lds[off];
  };

  // hoisted epilogue constants
  const int np = bn * 64 + wn * 16 + fc;
  const float bi = bias[np];
  const float bf_ = bias[512 + np];
  const float bg = bias[1024 + np];
  const float bo = bias[1536 + np];
  const size_t couts = (size_t)NB * HDIM;

  // prologue: stage tile 0 only (4 half-tiles), drain, barrier
  stA(0, 0); stA(0, 1); stB(0, 0); stB(0, 1);
  asm volatile("s_waitcnt vmcnt(0)" ::: "memory");
  SBAR();

#pragma unroll 2
  for (int t = 0; t < 64; ++t) {
    const int cb = t & 1;
    // ---- issue all 16 tile-reads: b0(4), ah0(8), b1(4); stage A(t+1) ----
#pragma unroll
    for (int nq = 0; nq < 2; ++nq)
#pragma unroll
      for (int ks = 0; ks < 2; ++ks) b0[nq][ks] = ldB(cb, 0, nq, ks);
#pragma unroll
    for (int mq = 0; mq < 4; ++mq)
#pragma unroll
      for (int ks = 0; ks < 2; ++ks) a[mq][ks] = ldA(cb, 0, mq, ks);
#pragma unroll
    for (int nq = 0; nq < 2; ++nq)
#pragma unroll
      for (int ks = 0; ks < 2; ++ks) b1[nq][ks] = ldB(cb, 1, nq, ks);
    stA(t + 1, 0);
    stA(t + 1, 1);
    // ---- Q1: MFMA(ah0,b0) ----
    asm volatile("s_waitcnt lgkmcnt(8)" ::: "memory");  // b0 + a[0..1]
    SCHED0();
    __builtin_amdgcn_s_setprio(1);
#pragma unroll
    for (int mq = 0; mq < 2; ++mq)
#pragma unroll
      for (int nq = 0; nq < 2; ++nq)
#pragma unroll
        for (int ks = 0; ks < 2; ++ks)
          MFMA16(a[mq][ks], b0[nq][ks], acc[mq][nq]);
    __builtin_amdgcn_s_setprio(0);
    asm volatile("s_waitcnt lgkmcnt(4)" ::: "memory");  // a[2..3]
    SCHED0();
    __builtin_amdgcn_s_setprio(1);
#pragma unroll
    for (int mq = 2; mq < 4; ++mq)
#pragma unroll
      for (int nq = 0; nq < 2; ++nq)
#pragma unroll
        for (int ks = 0; ks < 2; ++ks)
          MFMA16(a[mq][ks], b0[nq][ks], acc[mq][nq]);
    __builtin_amdgcn_s_setprio(0);
    stB(t + 1, 0);
    // ---- Q2: MFMA(ah0,b1) ----
    asm volatile("s_waitcnt lgkmcnt(0)" ::: "memory");  // b1
    SCHED0();
    __builtin_amdgcn_s_setprio(1);
#pragma unroll
    for (int mq = 0; mq < 4; ++mq)
#pragma unroll
      for (int nq = 0; nq < 2; ++nq)
#pragma unroll
        for (int ks = 0; ks < 2; ++ks)
          MFMA16(a[mq][ks], b1[nq][ks], acc[mq][2 + nq]);
    __builtin_amdgcn_s_setprio(0);
    // reload a <- A-h1 (8 reads; drains under Q2 tail / Q3 head)
#pragma unroll
    for (int mq = 0; mq < 4; ++mq)
#pragma unroll
      for (int ks = 0; ks < 2; ++ks) a[mq][ks] = ldA(cb, 1, mq, ks);
    stB(t + 1, 1);
    // ---- Q3: MFMA(ah1,b1) ----
    asm volatile("s_waitcnt lgkmcnt(4)" ::: "memory");  // a[0..1]
    SCHED0();
    __builtin_amdgcn_s_setprio(1);
#pragma unroll
    for (int mq = 0; mq < 2; ++mq)
#pragma unroll
      for (int nq = 0; nq < 2; ++nq)
#pragma unroll
        for (int ks = 0; ks < 2; ++ks)
          MFMA16(a[mq][ks], b1[nq][ks], acc[4 + mq][2 + nq]);
    __builtin_amdgcn_s_setprio(0);
    asm volatile("s_waitcnt lgkmcnt(0)" ::: "memory");  // a[2..3]
    SCHED0();
    __builtin_amdgcn_s_setprio(1);
#pragma unroll
    for (int mq = 2; mq < 4; ++mq)
#pragma unroll
      for (int nq = 0; nq < 2; ++nq)
#pragma unroll
        for (int ks = 0; ks < 2; ++ks)
          MFMA16(a[mq][ks], b1[nq][ks], acc[4 + mq][2 + nq]);
    __builtin_amdgcn_s_setprio(0);
    // ---- Q4: MFMA(ah1,b0) [all-register]; per-wave stage drain ----
    asm volatile("s_waitcnt vmcnt(0)" ::: "memory");  // t+1 stages complete
    __builtin_amdgcn_s_setprio(1);
#pragma unroll
    for (int mq = 0; mq < 4; ++mq)
#pragma unroll
      for (int nq = 0; nq < 2; ++nq)
#pragma unroll
        for (int ks = 0; ks < 2; ++ks)
          MFMA16(a[mq][ks], b0[nq][ks], acc[4 + mq][nq]);
    __builtin_amdgcn_s_setprio(0);
    SBAR();  // single barrier per K-tile

    // ---- inline LSTM epilogue at group end (regs+global only, no LDS) ----
    if ((t & 15) == 15) {
      const int g = t >> 4;
#pragma unroll
      for (int mf = 0; mf < 8; ++mf) {
        const int grow0 = ((bmg << 2) + g) * 256 + (mf >> 2) * 128 + wm * 64 +
                          (mf & 3) * 16 + fg * 4;
#pragma unroll
        for (int j = 0; j < 4; ++j) {
          const size_t off = (size_t)(grow0 + j) * HDIM + np;
          float i_ = fsigmoid(acc[mf][0][j] + bi);
          float f_ = fsigmoid(acc[mf][1][j] + bf_);
          float g_ = fsigmoid(acc[mf][2][j] + bg);
          float o_ = fsigmoid(acc[mf][3][j] + bo);
          float cp = f_ * cin[off] + i_ * g_;
          out[off] = o_ * ftanh(cp);
          out[couts + off] = cp;
        }
#pragma unroll
        for (int n = 0; n < 4; ++n) acc[mf][n] = (f32x4){0.f, 0.f, 0.f, 0.f};
      }
    }
  }
}

// ====================== launch ======================
extern "C" void kernel_launch(void* const* d_in, const int* in_sizes, int n_in,
                              void* d_out, int out_size, void* d_ws,
                              size_t ws_size, hipStream_t stream) {
  const float* xin = (const float*)d_in[0];
  const float* hin = (const float*)d_in[1];
  const float* cin = (const float*)d_in[2];
  WPtrs wp;
  wp.wi[0] = (const float*)d_in[3];
  wp.wi[1] = (const float*)d_in[7];
  wp.wi[2] = (const float*)d_in[11];
  wp.wi[3] = (const float*)d_in[15];
  wp.wh[0] = (const float*)d_in[4];
  wp.wh[1] = (const float*)d_in[8];
  wp.wh[2] = (const float*)d_in[12];
  wp.wh[3] = (const float*)d_in[16];
  BPtrs bp;
  bp.bi[0] = (const float*)d_in[5];
  bp.bi[1] = (const float*)d_in[9];
  bp.bi[2] = (const float*)d_in[13];
  bp.bi[3] = (const float*)d_in[17];
  bp.bh[0] = (const float*)d_in[6];
  bp.bh[1] = (const float*)d_in[10];
  bp.bh[2] = (const float*)d_in[14];
  bp.bh[3] = (const float*)d_in[18];

  const size_t needA = (size_t)NB * KDIM * 2;    // 64 MiB
  const size_t needW = (size_t)2048 * KDIM * 2;  // 4 MiB

  __bf16* Abf = (__bf16*)d_ws;
  __bf16* Wt = (__bf16*)((char*)d_ws + needA);
  float* bias = (float*)((char*)d_ws + needA + needW);

  conv_a_kernel<<<2048, 256, 0, stream>>>(xin, hin, Abf);
  pack_w2_kernel<<<dim3(16, 8, 4), 256, 0, stream>>>(wp, Wt);
  pack_bias_kernel<<<8, 256, 0, stream>>>(bp, bias);
  lstm_gemm5<<<256, 512, 0, stream>>>(Abf, Wt, cin, bias, (float*)d_out);
}